// Round 7
// baseline (2910.086 us; speedup 1.0000x reference)
//
#include <hip/hip_runtime.h>
#include <stdint.h>

// ---------------------------------------------------------------------------
// 2-layer LSTM (B=256, T=512, D_IN=64, H=512) + FC head, MI355X/gfx950.
// Round 22 = r21 (best, 2612us) + W_hh1 -> REGISTERS + DOUBLE-BUFFERED
// STAGING (one barrier/epoch).
//   Key identity: phase-2's B-operand rows for each lane (lr0, lr0+1 of the
//   htile slice) are EXACTLY wrow0/wrow1 -- the same rows the lane already
//   holds for wib1.  So W_hh1 moves to registers whh1[16][2], loaded like
//   wib1 from a linear bf16 copy (prep now writes linear, no swizzle).
//   - phase-2: 1 ds_read + 2 MFMA per kk (was 3 ds_reads + 2 MFMA)
//   - SQ_LDS_BANK_CONFLICT (7.5e7, 2/3 from phase-2 WhLds reads) mostly gone
//   - 128KB LDS freed -> hbufY/hbufH double-buffered (slot = e&1), barrier
//     B1 deleted.  Safety: every wave passes B2(e) before staging e+1, so
//     all reads of slot e&1 (epoch e) complete before the next write to it
//     (epoch e+2, which is after B2(e+1)).
//   At waves_per_eu(1,1) the unified VGPR budget is 512/lane: +128 regs ok.
// Everything else byte-identical to r21 (r15 exchange schedule + flags,
// transposed combine, shuffle-gather publish, sc0 sc1 ops).
// ---------------------------------------------------------------------------

typedef __bf16 bf16;
typedef bf16  bf16x8 __attribute__((ext_vector_type(8)));
typedef float f32x4  __attribute__((ext_vector_type(4)));
typedef unsigned int u32;
typedef unsigned long long u64;

#define NB   256
#define NT   512
#define NDIN 64
#define NH   512
#define POLL_GUARD (1 << 20)
#define SLOT_BYTES ((size_t)NB * NH * 2)          // 262144

// workspace layout (bytes)
static constexpr size_t OFF_XB   = 0;                                  // [B][T][64] bf16
static constexpr size_t OFF_WB0  = OFF_XB  + (size_t)NB*NT*NDIN*2;     // Whh0 bf16 [2048][512]
static constexpr size_t OFF_WI0  = OFF_WB0 + (size_t)2048*512*2;       // Wih0 bf16 [2048][64]
static constexpr size_t OFF_WI1  = OFF_WI0 + (size_t)2048*64*2;        // Wih1 bf16 [2048][512]
static constexpr size_t OFF_WH1  = OFF_WI1 + (size_t)2048*512*2;       // Whh1 bf16 linear [2048][512]
static constexpr size_t OFF_Y0R  = OFF_WH1 + (size_t)16*128*512*2;     // ys0 ring [2][B][H] bf16
static constexpr size_t OFF_R1   = OFF_Y0R + 2*SLOT_BYTES;             // h1  ring [2][B][H] bf16
static constexpr size_t OFF_HT   = OFF_R1  + 2*SLOT_BYTES;             // [B][H] f32
static constexpr size_t OFF_FLG  = OFF_HT  + (size_t)NB*NH*4;          // u32[16grp][16cons][64slot]
static constexpr size_t WS_NEED  = OFF_FLG + 65536;

#define MFMA16(a,b,c) __builtin_amdgcn_mfma_f32_16x16x32_bf16(a,b,c,0,0,0)

__device__ __forceinline__ float fsigm(float x) {
    return __builtin_amdgcn_rcpf(1.0f + __builtin_amdgcn_exp2f(x * -1.442695041f));
}
__device__ __forceinline__ float ftanh(float x) {
    return 1.0f - 2.0f * __builtin_amdgcn_rcpf(1.0f + __builtin_amdgcn_exp2f(x * 2.885390082f));
}
__device__ __forceinline__ u32 pack_bf16(float a, float b) {
    union { bf16 h[2]; u32 u; } un;
    un.h[0] = (bf16)a; un.h[1] = (bf16)b;
    return un.u;
}
__device__ __forceinline__ bf16x8 asf(int4 x) {
    union { int4 i; bf16x8 v; } u; u.i = x; return u.v;
}

// --- IC-coherent (sc0 sc1) batched exchange ops [proven r6/r8/r10] ---------
__device__ __forceinline__ void ld4_issue(const void* p0, const void* p1,
                                          const void* p2, const void* p3,
                                          int4& a, int4& b, int4& c, int4& d) {
    asm volatile(
        "global_load_dwordx4 %0, %4, off sc0 sc1\n\t"
        "global_load_dwordx4 %1, %5, off sc0 sc1\n\t"
        "global_load_dwordx4 %2, %6, off sc0 sc1\n\t"
        "global_load_dwordx4 %3, %7, off sc0 sc1"
        : "=&v"(a), "=&v"(b), "=&v"(c), "=&v"(d)
        : "v"(p0), "v"(p1), "v"(p2), "v"(p3)
        : "memory");
}
__device__ __forceinline__ void st64_cohr(void* p, u64 v) {
    asm volatile("global_store_dwordx2 %0, %1, off sc0 sc1" :: "v"(p), "v"(v) : "memory");
}
__device__ __forceinline__ void vm_drain() {      // rule #18: sched fence after waitcnt
    asm volatile("s_waitcnt vmcnt(0)" ::: "memory");
    __builtin_amdgcn_sched_barrier(0);
}
__device__ __forceinline__ void ld_fence() {
    asm volatile("" ::: "memory");
    __builtin_amdgcn_sched_barrier(0);
}
__device__ __forceinline__ void poll64(const u32* f, u32 target) {
    int guard = 0;
    while (__hip_atomic_load(f, __ATOMIC_RELAXED, __HIP_MEMORY_SCOPE_AGENT) < target)
        if (++guard > POLL_GUARD) break;   // wrong answer beats a hard hang
}
__device__ __forceinline__ void ast32(u32* p, u32 v) {
    __hip_atomic_store(p, v, __ATOMIC_RELAXED, __HIP_MEMORY_SCOPE_AGENT);
}

// ---------------------------------------------------------------------------
__global__ void xcvt_kernel(const float* __restrict__ x, char* __restrict__ ws) {
    size_t i = ((size_t)blockIdx.x * 256 + threadIdx.x) * 8;
    float4 a = *(const float4*)(x + i);
    float4 b = *(const float4*)(x + i + 4);
    u32 p0 = pack_bf16(a.x, a.y), p1 = pack_bf16(a.z, a.w);
    u32 p2 = pack_bf16(b.x, b.y), p3 = pack_bf16(b.z, b.w);
    *(int4*)(ws + OFF_XB + i * 2) = make_int4((int)p0, (int)p1, (int)p2, (int)p3);
}

__global__ void prep_kernel(const float* __restrict__ Wih0f, const float* __restrict__ Whh0f,
                            const float* __restrict__ Wih1f, const float* __restrict__ Whh1f,
                            char* __restrict__ ws) {
    int idx = blockIdx.x * 256 + threadIdx.x;       // 0 .. 1048575
    ((bf16*)(ws + OFF_WB0))[idx] = (bf16)Whh0f[idx];
    ((bf16*)(ws + OFF_WI1))[idx] = (bf16)Wih1f[idx];
    ((bf16*)(ws + OFF_WH1))[idx] = (bf16)Whh1f[idx];   // linear (regs now; no swizzle)
    if (idx < 2048 * 64) ((bf16*)(ws + OFF_WI0))[idx] = (bf16)Wih0f[idx];
}

// ---------------------------------------------------------------------------
// fused dual-layer LSTM: r21 + Whh1-in-regs + dbuf staging, 1 barrier (r22)
// ---------------------------------------------------------------------------
__global__ __attribute__((amdgpu_waves_per_eu(1, 1))) __launch_bounds__(256)
void lstm_fused(const float* __restrict__ b0, const float* __restrict__ b1,
                char* __restrict__ ws) {
    extern __shared__ char smem[];
    char* hbufY = smem;                // 2 x 16384: ys0[e-1] tiles (slot e&1)
    char* hbufH = smem + 32768;        // 2 x 16384: h1[e-2] tiles  (slot e&1)

    const int tid = threadIdx.x;
    const int v = tid >> 6, l = tid & 63;
    const int l15 = l & 15, lhi = l >> 4, g = l & 3, csel = l15 >> 2;
    const int group = blockIdx.x >> 4, htile = blockIdx.x & 15;
    const int b0r = group * 16, hs = htile * 32;

    const bf16* xb = (const bf16*)(ws + OFF_XB);
    char* y0r = ws + OFF_Y0R;
    char* r1  = ws + OFF_R1;
    float* hT = (float*)(ws + OFF_HT);
    u32* FL = (u32*)(ws + OFF_FLG);
    const u32* myLine = FL + ((size_t)group * 16 + htile) * 64;   // lane polls +l
    u32* peerF        = FL + (size_t)group * 1024 + htile * 4 + v; // + cons*64

    // lane -> output mapping (r8/r10): col n=l15 -> gate n&3, unit 8v+2*(n>>2)(+1)
    const int wrow0 = g * 512 + hs + 8 * v + 2 * csel;
    const int wrow1 = wrow0 + 1;

    const bf16* wb0p = (const bf16*)(ws + OFF_WB0);
    const bf16* wi0p = (const bf16*)(ws + OFF_WI0);
    const bf16* wi1p = (const bf16*)(ws + OFF_WI1);
    const bf16* wh1p = (const bf16*)(ws + OFF_WH1);
    int4 wb0[16][2], wib1[16][2], whh1[16][2];
#pragma unroll
    for (int kk = 0; kk < 16; ++kk) {
        wb0[kk][0]  = *(const int4*)(wb0p + (size_t)wrow0 * NH + kk * 32 + lhi * 8);
        wb0[kk][1]  = *(const int4*)(wb0p + (size_t)wrow1 * NH + kk * 32 + lhi * 8);
        wib1[kk][0] = *(const int4*)(wi1p + (size_t)wrow0 * NH + kk * 32 + lhi * 8);
        wib1[kk][1] = *(const int4*)(wi1p + (size_t)wrow1 * NH + kk * 32 + lhi * 8);
        whh1[kk][0] = *(const int4*)(wh1p + (size_t)wrow0 * NH + kk * 32 + lhi * 8);
        whh1[kk][1] = *(const int4*)(wh1p + (size_t)wrow1 * NH + kk * 32 + lhi * 8);
    }
    int4 wib0[2][2];
#pragma unroll
    for (int kk = 0; kk < 2; ++kk) {
        wib0[kk][0] = *(const int4*)(wi0p + (size_t)wrow0 * NDIN + kk * 32 + lhi * 8);
        wib0[kk][1] = *(const int4*)(wi0p + (size_t)wrow1 * NDIN + kk * 32 + lhi * 8);
    }
    const float b00 = b0[wrow0], b01 = b0[wrow1];
    const float b10 = b1[wrow0], b11 = b1[wrow1];

    // scalar cell states (one row per lane, transposed combine)
    float cA0s = 0.f, cA1s = 0.f, cB0s = 0.f, cB1s = 0.f;
    f32x4 aL00, aL01, aL10, aL11;
    const int srcl = csel * 16 + g;
    const int swz = (l15 & 7) << 4;
    const int r0i = tid >> 6;
    const int bc = (tid & 63) * 16;
    const bool o1 = (l & 1) != 0, o2 = (l & 2) != 0;

    int4 G0, G1, G2, G3;               // staged ys0 tile
    int4 H0, H1, H2, H3;               // staged h1 tile

    auto issueG = [&](int slot) {
        const char* p = y0r + (size_t)slot * SLOT_BYTES + (size_t)b0r * 1024
                      + (size_t)r0i * 1024 + bc;
        ld4_issue(p, p + 4096, p + 8192, p + 12288, G0, G1, G2, G3);
    };
    auto issueH = [&](int slot) {
        const char* p = r1 + (size_t)slot * SLOT_BYTES + (size_t)b0r * 1024
                      + (size_t)r0i * 1024 + bc;
        ld4_issue(p, p + 4096, p + 8192, p + 12288, H0, H1, H2, H3);
    };
    auto ldsWrite = [&](char* buf, int4 A, int4 B, int4 C, int4 D) {
        *(int4*)(buf + (r0i     ) * 1024 + (bc ^ (( r0i      & 7) << 4))) = A;
        *(int4*)(buf + (r0i +  4) * 1024 + (bc ^ (((r0i + 4) & 7) << 4))) = B;
        *(int4*)(buf + (r0i +  8) * 1024 + (bc ^ (( r0i      & 7) << 4))) = C;
        *(int4*)(buf + (r0i + 12) * 1024 + (bc ^ (((r0i + 4) & 7) << 4))) = D;
    };
    auto xproj0 = [&](int t) {
        const bf16* xp = xb + ((size_t)(b0r + l15) * NT + t) * NDIN + lhi * 8;
        bf16x8 xa0 = *(const bf16x8*)xp;
        bf16x8 xa1 = *(const bf16x8*)(xp + 32);
        aL00 = f32x4{b00, b00, b00, b00};
        aL01 = f32x4{b01, b01, b01, b01};
        aL00 = MFMA16(xa0, asf(wib0[0][0]), aL00); aL00 = MFMA16(xa1, asf(wib0[1][0]), aL00);
        aL01 = MFMA16(xa0, asf(wib0[0][1]), aL01); aL01 = MFMA16(xa1, asf(wib0[1][1]), aL01);
    };
    // transposed combine (r21): in-quad 4x4 butterfly; one cell update/lane
    auto combine = [&](const f32x4& a0, const f32x4& a1, float& cc0s, float& cc1s,
                       float& h0s, float& h1s) {
        float r0 = a0[0], r1v = a0[1], r2 = a0[2], r3 = a0[3];
        float q0 = a1[0], q1v = a1[1], q2 = a1[2], q3 = a1[3];
        float t;
        t = __shfl_xor(o1 ? r0 : r1v, 1); r0 = o1 ? t : r0;  r1v = o1 ? r1v : t;
        t = __shfl_xor(o1 ? r2 : r3, 1);  r2 = o1 ? t : r2;  r3  = o1 ? r3  : t;
        t = __shfl_xor(o2 ? r0 : r2, 2);  r0 = o2 ? t : r0;  r2  = o2 ? r2  : t;
        t = __shfl_xor(o2 ? r1v : r3, 2); r1v = o2 ? t : r1v; r3 = o2 ? r3  : t;
        t = __shfl_xor(o1 ? q0 : q1v, 1); q0 = o1 ? t : q0;  q1v = o1 ? q1v : t;
        t = __shfl_xor(o1 ? q2 : q3, 1);  q2 = o1 ? t : q2;  q3  = o1 ? q3  : t;
        t = __shfl_xor(o2 ? q0 : q2, 2);  q0 = o2 ? t : q0;  q2  = o2 ? q2  : t;
        t = __shfl_xor(o2 ? q1v : q3, 2); q1v = o2 ? t : q1v; q3 = o2 ? q3  : t;
        float cn0 = fsigm(r1v) * cc0s + fsigm(r0) * ftanh(r2);
        cc0s = cn0;
        h0s = fsigm(r3) * ftanh(cn0);
        float cn1 = fsigm(q1v) * cc1s + fsigm(q0) * ftanh(q2);
        cc1s = cn1;
        h1s = fsigm(q3) * ftanh(cn1);
    };
    auto publish = [&](float h0s, float h1s, char* tileBase) {
        u32 pk = pack_bf16(h0s, h1s);
        u32 w0 = __shfl(pk, srcl),     w1 = __shfl(pk, srcl + 4);
        u32 w2 = __shfl(pk, srcl + 8), w3 = __shfl(pk, srcl + 12);
        if (l < 16) {
            char* rp = tileBase + (size_t)l * 1024 + hs * 2 + v * 16;
            union { u32 w[2]; u64 q; } qa, qb2;
            qa.w[0] = w0; qa.w[1] = w1; qb2.w[0] = w2; qb2.w[1] = w3;
            st64_cohr(rp, qa.q); st64_cohr(rp + 8, qb2.q);
        }
    };
    auto setF = [&](u32 val) {     // per-wave: after own vm_drain only
        if (l < 16) ast32(peerF + (size_t)l * 64, val);
    };

    // ---- epoch 0: layer0 step 0 only --------------------------------------
    xproj0(0);
    {
        float h0s, h1s;
        combine(aL00, aL01, cA0s, cA1s, h0s, h1s);
        publish(h0s, h1s, y0r + (size_t)b0r * 1024);     // ys0[0] slot 0
        vm_drain();
        setF(1u);
        xproj0(1);
    }

    // ---- epochs 1..NT ------------------------------------------------------
    for (int e = 1; e <= NT; ++e) {
        const bool doL0 = (e < NT);
        const bool doH1 = (e >= 2);
        const int sl = e & 1;          // staging slot parity

        poll64(myLine + l, (u32)e);    // single poll point (r10-style)
        ld_fence();
        issueG((e - 1) & 1);
        if (doH1) issueH(e & 1);
        vm_drain();

        // double-buffered staging: no pre-barrier needed (slot parity
        // disjoint from stragglers' reads; see header safety argument)
        ldsWrite(hbufY + sl * 16384, G0, G1, G2, G3);
        if (doH1) ldsWrite(hbufH + sl * 16384, H0, H1, H2, H3);
        __syncthreads();               // B2: tiles ready

        // phase-1: layer0-h (wb0) + layer1-x (wib1), shared A-frags from hbufY
        const char* hY = hbufY + sl * 16384;
        aL10 = f32x4{b10, b10, b10, b10};
        aL11 = f32x4{b11, b11, b11, b11};
#pragma unroll
        for (int kk = 0; kk < 16; ++kk) {
            bf16x8 ha = *(const bf16x8*)(hY + l15 * 1024 + ((kk * 64 + lhi * 16) ^ swz));
            if (doL0) {
                aL00 = MFMA16(ha, asf(wb0[kk][0]), aL00);
                aL01 = MFMA16(ha, asf(wb0[kk][1]), aL01);
            }
            aL10 = MFMA16(ha, asf(wib1[kk][0]), aL10);
            aL11 = MFMA16(ha, asf(wib1[kk][1]), aL11);
        }

        if (doL0) {                    // layer0 combine + publish (no drain yet:
            float h0s, h1s;            //  store latency hides under phase-2)
            combine(aL00, aL01, cA0s, cA1s, h0s, h1s);
            publish(h0s, h1s, y0r + (size_t)(e & 1) * SLOT_BYTES + (size_t)b0r * 1024);
        }

        if (doH1) {                    // phase-2: layer1-h, A=hbufH, B=whh1 regs
            const char* hH = hbufH + sl * 16384;
#pragma unroll
            for (int kk = 0; kk < 16; ++kk) {
                int kb = kk * 64 + lhi * 16;
                bf16x8 a = *(const bf16x8*)(hH + l15 * 1024 + (kb ^ swz));
                aL10 = MFMA16(a, asf(whh1[kk][0]), aL10);
                aL11 = MFMA16(a, asf(whh1[kk][1]), aL11);
            }
        }

        {                              // layer1 combine + publish h1(e-1)
            float h0s, h1s;
            combine(aL10, aL11, cB0s, cB1s, h0s, h1s);
            if (e < NT) {
                publish(h0s, h1s, r1 + (size_t)((e - 1) & 1) * SLOT_BYTES + (size_t)b0r * 1024);
            } else {                   // final hidden state, f32
                float* hp = hT + (size_t)(b0r + lhi * 4 + g) * NH + hs + 8 * v + 2 * csel;
                hp[0] = h0s; hp[1] = h1s;
            }
        }
        if (e < NT) {
            vm_drain();                // both publishes acked at IC
            setF((u32)(e + 1));        // per-wave flag
            xproj0(e + 1);             // next layer0 x-proj under peers' skew
        }
    }
}

// ---------------------------------------------------------------------------
__global__ __launch_bounds__(256) void fc_kernel(const float* __restrict__ fc1_w,
                                                 const float* __restrict__ fc1_b,
                                                 const float* __restrict__ fc_w,
                                                 const float* __restrict__ fc_b,
                                                 const char* __restrict__ ws,
                                                 float* __restrict__ out) {
    __shared__ float hLds[512];
    __shared__ float red[256];
    const int b = blockIdx.x, tid = threadIdx.x;
    const float* hT = (const float*)(ws + OFF_HT) + (size_t)b * NH;
    hLds[tid]       = hT[tid];
    hLds[tid + 256] = hT[tid + 256];
    __syncthreads();
    float p = 0.f;
#pragma unroll
    for (int rep = 0; rep < 2; ++rep) {
        int hh = tid + rep * 256;
        const float* wr = fc1_w + (size_t)hh * 512;
        float s = fc1_b[hh];
        for (int k = 0; k < 512; k += 4) {
            float4 w4 = *(const float4*)(wr + k);
            s += hLds[k] * w4.x + hLds[k + 1] * w4.y + hLds[k + 2] * w4.z + hLds[k + 3] * w4.w;
        }
        s = fmaxf(s, 0.f);
        p += s * fc_w[hh];
    }
    red[tid] = p;
    __syncthreads();
    for (int off = 128; off > 0; off >>= 1) {
        if (tid < off) red[tid] += red[tid + off];
        __syncthreads();
    }
    if (tid == 0) out[b] = fmaxf(red[0] + fc_b[0], 0.f);
}

// ---------------------------------------------------------------------------
extern "C" void kernel_launch(void* const* d_in, const int* in_sizes, int n_in,
                              void* d_out, int out_size, void* d_ws, size_t ws_size,
                              hipStream_t stream) {
    const float* x    = (const float*)d_in[0];
    const float* Wih0 = (const float*)d_in[1];
    const float* Whh0 = (const float*)d_in[2];
    const float* b0   = (const float*)d_in[3];
    const float* Wih1 = (const float*)d_in[4];
    const float* Whh1 = (const float*)d_in[5];
    const float* b1   = (const float*)d_in[6];
    const float* fc1w = (const float*)d_in[7];
    const float* fc1b = (const float*)d_in[8];
    const float* fcw  = (const float*)d_in[9];
    const float* fcb  = (const float*)d_in[10];
    char* ws = (char*)d_ws;
    float* out = (float*)d_out;

    if (ws_size < WS_NEED) {
        (void)hipMemsetAsync(d_out, 0, (size_t)out_size * 4, stream);
        return;
    }

    // flags must be zero every call (graph replays re-run this)
    (void)hipMemsetAsync(ws + OFF_FLG, 0, 65536, stream);

    hipLaunchKernelGGL(xcvt_kernel, dim3(4096), dim3(256), 0, stream, x, ws);
    hipLaunchKernelGGL(prep_kernel, dim3(4096), dim3(256), 0, stream,
                       Wih0, Whh0, Wih1, Whh1, ws);
    hipLaunchKernelGGL(lstm_fused, dim3(256), dim3(256), 65536, stream, b0, b1, ws);
    hipLaunchKernelGGL(fc_kernel, dim3(256), dim3(256), 0, stream,
                       fc1w, fc1b, fcw, fcb, ws, out);
}

// Round 8
// 2527.121 us; speedup vs baseline: 1.1515x; 1.1515x over previous
//
#include <hip/hip_runtime.h>
#include <stdint.h>

// ---------------------------------------------------------------------------
// 2-layer LSTM (B=256, T=512, D_IN=64, H=512) + FC head, MI355X/gfx950.
// Round 23 = r21 (best, 2612us) + PACKED FLAG LINES + SPLIT STAGING DRAIN.
//   r22 post-mortem: VGPR 256 cap caused the regression; bank conflicts
//   unchanged after WhLds removal -> they are the staging-throughput floor,
//   not a fixable aliasing. Whh1 stays in LDS (r21 form).
//   Change 1: r17-proven packed flag lines. setF = ONE store/wave (lane 0)
//     to the group's shared 64-slot line instead of 16 scattered 4B stores
//     256B apart. Removes ~15 serial store-issues from the producer chain
//     and makes the last-flag-land (which gates every consumer) earlier.
//     Poll: lane l polls slot l of the shared line (r17 addressing,
//     protocol values/set-points identical to r15/r21).
//   Change 2: top-of-epoch drain split: issueG+issueH -> vmcnt(4) -> stage
//     G -> vmcnt(0) -> stage H (H flight overlaps G's LDS writes).
// Everything else byte-identical to r21 (r15 exchange schedule, transposed
// combine, shuffle-gather publish, sc0 sc1 ops, Whh1 LDS swizzle).
// ---------------------------------------------------------------------------

typedef __bf16 bf16;
typedef bf16  bf16x8 __attribute__((ext_vector_type(8)));
typedef float f32x4  __attribute__((ext_vector_type(4)));
typedef unsigned int u32;
typedef unsigned long long u64;

#define NB   256
#define NT   512
#define NDIN 64
#define NH   512
#define POLL_GUARD (1 << 20)
#define SLOT_BYTES ((size_t)NB * NH * 2)          // 262144

// workspace layout (bytes)
static constexpr size_t OFF_XB   = 0;                                  // [B][T][64] bf16
static constexpr size_t OFF_WB0  = OFF_XB  + (size_t)NB*NT*NDIN*2;     // Whh0 bf16 [2048][512]
static constexpr size_t OFF_WI0  = OFF_WB0 + (size_t)2048*512*2;       // Wih0 bf16 [2048][64]
static constexpr size_t OFF_WI1  = OFF_WI0 + (size_t)2048*64*2;        // Wih1 bf16 [2048][512]
static constexpr size_t OFF_WHS1 = OFF_WI1 + (size_t)2048*512*2;       // Whh1 swizzled slices
static constexpr size_t OFF_Y0R  = OFF_WHS1+ (size_t)16*128*512*2;     // ys0 ring [2][B][H] bf16
static constexpr size_t OFF_R1   = OFF_Y0R + 2*SLOT_BYTES;             // h1  ring [2][B][H] bf16
static constexpr size_t OFF_HT   = OFF_R1  + 2*SLOT_BYTES;             // [B][H] f32
static constexpr size_t OFF_FLG  = OFF_HT  + (size_t)NB*NH*4;          // u32[16grp][64slot] = 4KB
static constexpr size_t WS_NEED  = OFF_FLG + 4096;

#define MFMA16(a,b,c) __builtin_amdgcn_mfma_f32_16x16x32_bf16(a,b,c,0,0,0)

__device__ __forceinline__ float fsigm(float x) {
    return __builtin_amdgcn_rcpf(1.0f + __builtin_amdgcn_exp2f(x * -1.442695041f));
}
__device__ __forceinline__ float ftanh(float x) {
    return 1.0f - 2.0f * __builtin_amdgcn_rcpf(1.0f + __builtin_amdgcn_exp2f(x * 2.885390082f));
}
__device__ __forceinline__ u32 pack_bf16(float a, float b) {
    union { bf16 h[2]; u32 u; } un;
    un.h[0] = (bf16)a; un.h[1] = (bf16)b;
    return un.u;
}
__device__ __forceinline__ bf16x8 asf(int4 x) {
    union { int4 i; bf16x8 v; } u; u.i = x; return u.v;
}

// --- IC-coherent (sc0 sc1) batched exchange ops [proven r6/r8/r10] ---------
__device__ __forceinline__ void ld4_issue(const void* p0, const void* p1,
                                          const void* p2, const void* p3,
                                          int4& a, int4& b, int4& c, int4& d) {
    asm volatile(
        "global_load_dwordx4 %0, %4, off sc0 sc1\n\t"
        "global_load_dwordx4 %1, %5, off sc0 sc1\n\t"
        "global_load_dwordx4 %2, %6, off sc0 sc1\n\t"
        "global_load_dwordx4 %3, %7, off sc0 sc1"
        : "=&v"(a), "=&v"(b), "=&v"(c), "=&v"(d)
        : "v"(p0), "v"(p1), "v"(p2), "v"(p3)
        : "memory");
}
__device__ __forceinline__ void st64_cohr(void* p, u64 v) {
    asm volatile("global_store_dwordx2 %0, %1, off sc0 sc1" :: "v"(p), "v"(v) : "memory");
}
__device__ __forceinline__ void vm_drain() {      // rule #18: sched fence after waitcnt
    asm volatile("s_waitcnt vmcnt(0)" ::: "memory");
    __builtin_amdgcn_sched_barrier(0);
}
__device__ __forceinline__ void vm_wait4() {      // <=4 outstanding (G arrived, H in flight)
    asm volatile("s_waitcnt vmcnt(4)" ::: "memory");
    __builtin_amdgcn_sched_barrier(0);
}
__device__ __forceinline__ void ld_fence() {
    asm volatile("" ::: "memory");
    __builtin_amdgcn_sched_barrier(0);
}
__device__ __forceinline__ void poll64(const u32* f, u32 target) {
    int guard = 0;
    while (__hip_atomic_load(f, __ATOMIC_RELAXED, __HIP_MEMORY_SCOPE_AGENT) < target)
        if (++guard > POLL_GUARD) break;   // wrong answer beats a hard hang
}
__device__ __forceinline__ void ast32(u32* p, u32 v) {
    __hip_atomic_store(p, v, __ATOMIC_RELAXED, __HIP_MEMORY_SCOPE_AGENT);
}

// W_hh1 LDS swizzle slot for local row lr [proven r8/r10]
__device__ __forceinline__ int wslot(int lr) {
    return ((lr >> 5) & 3) | (((lr >> 1) & 3) << 2);
}

// ---------------------------------------------------------------------------
__global__ void xcvt_kernel(const float* __restrict__ x, char* __restrict__ ws) {
    size_t i = ((size_t)blockIdx.x * 256 + threadIdx.x) * 8;
    float4 a = *(const float4*)(x + i);
    float4 b = *(const float4*)(x + i + 4);
    u32 p0 = pack_bf16(a.x, a.y), p1 = pack_bf16(a.z, a.w);
    u32 p2 = pack_bf16(b.x, b.y), p3 = pack_bf16(b.z, b.w);
    *(int4*)(ws + OFF_XB + i * 2) = make_int4((int)p0, (int)p1, (int)p2, (int)p3);
}

__global__ void prep_kernel(const float* __restrict__ Wih0f, const float* __restrict__ Whh0f,
                            const float* __restrict__ Wih1f, const float* __restrict__ Whh1f,
                            char* __restrict__ ws) {
    int idx = blockIdx.x * 256 + threadIdx.x;       // 0 .. 1048575
    ((bf16*)(ws + OFF_WB0))[idx] = (bf16)Whh0f[idx];
    ((bf16*)(ws + OFF_WI1))[idx] = (bf16)Wih1f[idx];
    if (idx < 2048 * 64) ((bf16*)(ws + OFF_WI0))[idx] = (bf16)Wih0f[idx];
    int slice = idx >> 16;
    int lr    = (idx >> 9) & 127;
    int k     = idx & 511;
    int grow  = (lr >> 5) * 512 + slice * 32 + (lr & 31);
    ((bf16*)(ws + OFF_WHS1))[(size_t)slice * 65536 + lr * 512 + (k ^ (wslot(lr) << 3))] =
        (bf16)Whh1f[(size_t)grow * 512 + k];
}

// ---------------------------------------------------------------------------
// fused dual-layer LSTM: r21 + packed flags + split staging drain (r23)
// ---------------------------------------------------------------------------
__global__ __attribute__((amdgpu_waves_per_eu(1, 1))) __launch_bounds__(256)
void lstm_fused(const float* __restrict__ b0, const float* __restrict__ b1,
                char* __restrict__ ws) {
    extern __shared__ char smem[];
    char* WhLds = smem;                // 131072: W_hh1 slice (read-only in loop)
    char* hbufY = smem + 131072;       // 16384: ys0[e-1] tile
    char* hbufH = smem + 147456;       // 16384: h1[e-2] tile

    const int tid = threadIdx.x;
    const int v = tid >> 6, l = tid & 63;
    const int l15 = l & 15, lhi = l >> 4, g = l & 3, csel = l15 >> 2;
    const int group = blockIdx.x >> 4, htile = blockIdx.x & 15;
    const int b0r = group * 16, hs = htile * 32;

    const bf16* xb = (const bf16*)(ws + OFF_XB);
    char* y0r = ws + OFF_Y0R;
    char* r1  = ws + OFF_R1;
    float* hT = (float*)(ws + OFF_HT);
    u32* FL = (u32*)(ws + OFF_FLG);
    // packed shared flag line per group (r17-proven): slot s = htile*4 + v
    // written by that producer wave's lane 0; every consumer lane l polls slot l.
    const u32* myLine = FL + (size_t)group * 64;
    u32* peerF        = FL + (size_t)group * 64 + htile * 4 + v;

    // stage pre-swizzled W_hh1 slice -> LDS (written once; read-only in loop)
    {
        const char* wsrc = ws + OFF_WHS1 + (size_t)htile * 131072;
#pragma unroll
        for (int i = 0; i < 32; ++i) {
            int off = (tid + i * 256) * 16;
            *(int4*)(WhLds + off) = *(const int4*)(wsrc + off);
        }
    }

    // lane -> output mapping (r8/r10): col n=l15 -> gate n&3, unit 8v+2*(n>>2)(+1)
    const int wrow0 = g * 512 + hs + 8 * v + 2 * csel;
    const int wrow1 = wrow0 + 1;

    const bf16* wb0p = (const bf16*)(ws + OFF_WB0);
    const bf16* wi0p = (const bf16*)(ws + OFF_WI0);
    const bf16* wi1p = (const bf16*)(ws + OFF_WI1);
    int4 wb0[16][2], wib1[16][2];
#pragma unroll
    for (int kk = 0; kk < 16; ++kk) {
        wb0[kk][0]  = *(const int4*)(wb0p + (size_t)wrow0 * NH + kk * 32 + lhi * 8);
        wb0[kk][1]  = *(const int4*)(wb0p + (size_t)wrow1 * NH + kk * 32 + lhi * 8);
        wib1[kk][0] = *(const int4*)(wi1p + (size_t)wrow0 * NH + kk * 32 + lhi * 8);
        wib1[kk][1] = *(const int4*)(wi1p + (size_t)wrow1 * NH + kk * 32 + lhi * 8);
    }
    int4 wib0[2][2];
#pragma unroll
    for (int kk = 0; kk < 2; ++kk) {
        wib0[kk][0] = *(const int4*)(wi0p + (size_t)wrow0 * NDIN + kk * 32 + lhi * 8);
        wib0[kk][1] = *(const int4*)(wi0p + (size_t)wrow1 * NDIN + kk * 32 + lhi * 8);
    }
    const float b00 = b0[wrow0], b01 = b0[wrow1];
    const float b10 = b1[wrow0], b11 = b1[wrow1];

    // scalar cell states (one row per lane, transposed combine)
    float cA0s = 0.f, cA1s = 0.f, cB0s = 0.f, cB1s = 0.f;
    f32x4 aL00, aL01, aL10, aL11;
    const int srcl = csel * 16 + g;
    const int swz = (l15 & 7) << 4;
    const int lr0 = g * 32 + 8 * v + 2 * csel;
    const int wsw = wslot(lr0) << 4;
    const int r0i = tid >> 6;
    const int bc = (tid & 63) * 16;
    const bool o1 = (l & 1) != 0, o2 = (l & 2) != 0;

    int4 G0, G1, G2, G3;               // staged ys0 tile
    int4 H0, H1, H2, H3;               // staged h1 tile

    auto issueG = [&](int slot) {
        const char* p = y0r + (size_t)slot * SLOT_BYTES + (size_t)b0r * 1024
                      + (size_t)r0i * 1024 + bc;
        ld4_issue(p, p + 4096, p + 8192, p + 12288, G0, G1, G2, G3);
    };
    auto issueH = [&](int slot) {
        const char* p = r1 + (size_t)slot * SLOT_BYTES + (size_t)b0r * 1024
                      + (size_t)r0i * 1024 + bc;
        ld4_issue(p, p + 4096, p + 8192, p + 12288, H0, H1, H2, H3);
    };
    auto ldsWrite = [&](char* buf, int4 A, int4 B, int4 C, int4 D) {
        *(int4*)(buf + (r0i     ) * 1024 + (bc ^ (( r0i      & 7) << 4))) = A;
        *(int4*)(buf + (r0i +  4) * 1024 + (bc ^ (((r0i + 4) & 7) << 4))) = B;
        *(int4*)(buf + (r0i +  8) * 1024 + (bc ^ (( r0i      & 7) << 4))) = C;
        *(int4*)(buf + (r0i + 12) * 1024 + (bc ^ (((r0i + 4) & 7) << 4))) = D;
    };
    auto xproj0 = [&](int t) {
        const bf16* xp = xb + ((size_t)(b0r + l15) * NT + t) * NDIN + lhi * 8;
        bf16x8 xa0 = *(const bf16x8*)xp;
        bf16x8 xa1 = *(const bf16x8*)(xp + 32);
        aL00 = f32x4{b00, b00, b00, b00};
        aL01 = f32x4{b01, b01, b01, b01};
        aL00 = MFMA16(xa0, asf(wib0[0][0]), aL00); aL00 = MFMA16(xa1, asf(wib0[1][0]), aL00);
        aL01 = MFMA16(xa0, asf(wib0[0][1]), aL01); aL01 = MFMA16(xa1, asf(wib0[1][1]), aL01);
    };
    // transposed combine (r21): in-quad 4x4 butterfly; one cell update/lane
    auto combine = [&](const f32x4& a0, const f32x4& a1, float& cc0s, float& cc1s,
                       float& h0s, float& h1s) {
        float r0 = a0[0], r1v = a0[1], r2 = a0[2], r3 = a0[3];
        float q0 = a1[0], q1v = a1[1], q2 = a1[2], q3 = a1[3];
        float t;
        t = __shfl_xor(o1 ? r0 : r1v, 1); r0 = o1 ? t : r0;  r1v = o1 ? r1v : t;
        t = __shfl_xor(o1 ? r2 : r3, 1);  r2 = o1 ? t : r2;  r3  = o1 ? r3  : t;
        t = __shfl_xor(o2 ? r0 : r2, 2);  r0 = o2 ? t : r0;  r2  = o2 ? r2  : t;
        t = __shfl_xor(o2 ? r1v : r3, 2); r1v = o2 ? t : r1v; r3 = o2 ? r3  : t;
        t = __shfl_xor(o1 ? q0 : q1v, 1); q0 = o1 ? t : q0;  q1v = o1 ? q1v : t;
        t = __shfl_xor(o1 ? q2 : q3, 1);  q2 = o1 ? t : q2;  q3  = o1 ? q3  : t;
        t = __shfl_xor(o2 ? q0 : q2, 2);  q0 = o2 ? t : q0;  q2  = o2 ? q2  : t;
        t = __shfl_xor(o2 ? q1v : q3, 2); q1v = o2 ? t : q1v; q3 = o2 ? q3  : t;
        float cn0 = fsigm(r1v) * cc0s + fsigm(r0) * ftanh(r2);
        cc0s = cn0;
        h0s = fsigm(r3) * ftanh(cn0);
        float cn1 = fsigm(q1v) * cc1s + fsigm(q0) * ftanh(q2);
        cc1s = cn1;
        h1s = fsigm(q3) * ftanh(cn1);
    };
    auto publish = [&](float h0s, float h1s, char* tileBase) {
        u32 pk = pack_bf16(h0s, h1s);
        u32 w0 = __shfl(pk, srcl),     w1 = __shfl(pk, srcl + 4);
        u32 w2 = __shfl(pk, srcl + 8), w3 = __shfl(pk, srcl + 12);
        if (l < 16) {
            char* rp = tileBase + (size_t)l * 1024 + hs * 2 + v * 16;
            union { u32 w[2]; u64 q; } qa, qb2;
            qa.w[0] = w0; qa.w[1] = w1; qb2.w[0] = w2; qb2.w[1] = w3;
            st64_cohr(rp, qa.q); st64_cohr(rp + 8, qb2.q);
        }
    };
    auto setF = [&](u32 val) {     // per-wave: after own vm_drain only; ONE store
        if (l == 0) ast32(peerF, val);
    };

    __syncthreads();    // WhLds ready

    // ---- epoch 0: layer0 step 0 only --------------------------------------
    xproj0(0);
    {
        float h0s, h1s;
        combine(aL00, aL01, cA0s, cA1s, h0s, h1s);
        publish(h0s, h1s, y0r + (size_t)b0r * 1024);     // ys0[0] slot 0
        vm_drain();
        setF(1u);
        xproj0(1);
    }

    // ---- epochs 1..NT ------------------------------------------------------
    for (int e = 1; e <= NT; ++e) {
        const bool doL0 = (e < NT);
        const bool doH1 = (e >= 2);

        poll64(myLine + l, (u32)e);    // single poll point (r10-style)
        ld_fence();
        issueG((e - 1) & 1);
        if (doH1) {
            issueH(e & 1);
            __syncthreads();           // B1: prev epoch's hbuf readers done
            vm_wait4();                // G arrived; H still in flight
            ldsWrite(hbufY, G0, G1, G2, G3);
            vm_drain();                // H arrived
            ldsWrite(hbufH, H0, H1, H2, H3);
        } else {
            __syncthreads();           // B1
            vm_drain();
            ldsWrite(hbufY, G0, G1, G2, G3);
        }
        __syncthreads();               // B2: both tiles ready

        // phase-1: layer0-h (wb0) + layer1-x (wib1), shared A-frags from hbufY
        aL10 = f32x4{b10, b10, b10, b10};
        aL11 = f32x4{b11, b11, b11, b11};
#pragma unroll
        for (int kk = 0; kk < 16; ++kk) {
            bf16x8 ha = *(const bf16x8*)(hbufY + l15 * 1024 + ((kk * 64 + lhi * 16) ^ swz));
            if (doL0) {
                aL00 = MFMA16(ha, asf(wb0[kk][0]), aL00);
                aL01 = MFMA16(ha, asf(wb0[kk][1]), aL01);
            }
            aL10 = MFMA16(ha, asf(wib1[kk][0]), aL10);
            aL11 = MFMA16(ha, asf(wib1[kk][1]), aL11);
        }

        if (doL0) {                    // layer0 combine + publish (no drain yet:
            float h0s, h1s;            //  store latency hides under phase-2)
            combine(aL00, aL01, cA0s, cA1s, h0s, h1s);
            publish(h0s, h1s, y0r + (size_t)(e & 1) * SLOT_BYTES + (size_t)b0r * 1024);
        }

        if (doH1) {                    // phase-2: layer1-h, A=hbufH, B=W_hh1
#pragma unroll
            for (int kk = 0; kk < 16; ++kk) {
                int kb = kk * 64 + lhi * 16;
                bf16x8 a  = *(const bf16x8*)(hbufH + l15 * 1024 + (kb ^ swz));
                bf16x8 w0 = *(const bf16x8*)(WhLds + (size_t) lr0      * 1024 + (kb ^ wsw));
                bf16x8 w1 = *(const bf16x8*)(WhLds + (size_t)(lr0 + 1) * 1024 + (kb ^ wsw));
                aL10 = MFMA16(a, w0, aL10);
                aL11 = MFMA16(a, w1, aL11);
            }
        }

        {                              // layer1 combine + publish h1(e-1)
            float h0s, h1s;
            combine(aL10, aL11, cB0s, cB1s, h0s, h1s);
            if (e < NT) {
                publish(h0s, h1s, r1 + (size_t)((e - 1) & 1) * SLOT_BYTES + (size_t)b0r * 1024);
            } else {                   // final hidden state, f32
                float* hp = hT + (size_t)(b0r + lhi * 4 + g) * NH + hs + 8 * v + 2 * csel;
                hp[0] = h0s; hp[1] = h1s;
            }
        }
        if (e < NT) {
            vm_drain();                // both publishes acked at IC
            setF((u32)(e + 1));        // ONE flag store/wave
            xproj0(e + 1);             // next layer0 x-proj under peers' skew
        }
    }
}

// ---------------------------------------------------------------------------
__global__ __launch_bounds__(256) void fc_kernel(const float* __restrict__ fc1_w,
                                                 const float* __restrict__ fc1_b,
                                                 const float* __restrict__ fc_w,
                                                 const float* __restrict__ fc_b,
                                                 const char* __restrict__ ws,
                                                 float* __restrict__ out) {
    __shared__ float hLds[512];
    __shared__ float red[256];
    const int b = blockIdx.x, tid = threadIdx.x;
    const float* hT = (const float*)(ws + OFF_HT) + (size_t)b * NH;
    hLds[tid]       = hT[tid];
    hLds[tid + 256] = hT[tid + 256];
    __syncthreads();
    float p = 0.f;
#pragma unroll
    for (int rep = 0; rep < 2; ++rep) {
        int hh = tid + rep * 256;
        const float* wr = fc1_w + (size_t)hh * 512;
        float s = fc1_b[hh];
        for (int k = 0; k < 512; k += 4) {
            float4 w4 = *(const float4*)(wr + k);
            s += hLds[k] * w4.x + hLds[k + 1] * w4.y + hLds[k + 2] * w4.z + hLds[k + 3] * w4.w;
        }
        s = fmaxf(s, 0.f);
        p += s * fc_w[hh];
    }
    red[tid] = p;
    __syncthreads();
    for (int off = 128; off > 0; off >>= 1) {
        if (tid < off) red[tid] += red[tid + off];
        __syncthreads();
    }
    if (tid == 0) out[b] = fmaxf(red[0] + fc_b[0], 0.f);
}

// ---------------------------------------------------------------------------
extern "C" void kernel_launch(void* const* d_in, const int* in_sizes, int n_in,
                              void* d_out, int out_size, void* d_ws, size_t ws_size,
                              hipStream_t stream) {
    const float* x    = (const float*)d_in[0];
    const float* Wih0 = (const float*)d_in[1];
    const float* Whh0 = (const float*)d_in[2];
    const float* b0   = (const float*)d_in[3];
    const float* Wih1 = (const float*)d_in[4];
    const float* Whh1 = (const float*)d_in[5];
    const float* b1   = (const float*)d_in[6];
    const float* fc1w = (const float*)d_in[7];
    const float* fc1b = (const float*)d_in[8];
    const float* fcw  = (const float*)d_in[9];
    const float* fcb  = (const float*)d_in[10];
    char* ws = (char*)d_ws;
    float* out = (float*)d_out;

    if (ws_size < WS_NEED) {
        (void)hipMemsetAsync(d_out, 0, (size_t)out_size * 4, stream);
        return;
    }

    // flags must be zero every call (graph replays re-run this)
    (void)hipMemsetAsync(ws + OFF_FLG, 0, 4096, stream);

    hipLaunchKernelGGL(xcvt_kernel, dim3(4096), dim3(256), 0, stream, x, ws);
    hipLaunchKernelGGL(prep_kernel, dim3(4096), dim3(256), 0, stream,
                       Wih0, Whh0, Wih1, Whh1, ws);
    hipLaunchKernelGGL(lstm_fused, dim3(256), dim3(256), 163840, stream, b0, b1, ws);
    hipLaunchKernelGGL(fc_kernel, dim3(256), dim3(256), 0, stream,
                       fc1w, fc1b, fcw, fcb, ws, out);
}